// Round 1
// baseline (1326.425 us; speedup 1.0000x reference)
//
#include <hip/hip_runtime.h>

#define B_ 8
#define C_ 128
#define W_ 4096
#define D_ 16
// 0.25 (=D^-0.5) * log2(e): work in exp2 domain so exp2f -> v_exp_f32
#define SCALE2 0.3606737602222409f

// ---------------- Kernel A: q,k projection ----------------
// q[b,d,w] = sum_c Wq[d,c] x[b,c,w] + bq[d]; stored as qws[b][w][d] (fp32)
// block 128 threads, grid B*W/128 = 256; one thread per (b,w)
__global__ __launch_bounds__(128) void qk_proj(
    const float* __restrict__ x, const float* __restrict__ Wq, const float* __restrict__ bq,
    const float* __restrict__ Wk, const float* __restrict__ bk,
    float* __restrict__ qws, float* __restrict__ kws)
{
    int g = blockIdx.x * 128 + threadIdx.x;
    int b = g >> 12;
    int w = g & (W_ - 1);
    const float* xp = x + (size_t)b * C_ * W_ + w;
    float qa[D_], ka[D_];
#pragma unroll
    for (int d = 0; d < D_; d++) { qa[d] = bq[d]; ka[d] = bk[d]; }

    for (int c0 = 0; c0 < C_; c0 += 16) {
        float xv[16];
#pragma unroll
        for (int cc = 0; cc < 16; cc++) xv[cc] = xp[(size_t)(c0 + cc) * W_];
#pragma unroll 4
        for (int d = 0; d < D_; d++) {
            const float* wqr = Wq + d * C_ + c0;
            const float* wkr = Wk + d * C_ + c0;
#pragma unroll
            for (int c4 = 0; c4 < 4; c4++) {
                float4 a = *(const float4*)(wqr + c4 * 4);
                float4 bb = *(const float4*)(wkr + c4 * 4);
                qa[d] += a.x * xv[c4*4+0] + a.y * xv[c4*4+1] + a.z * xv[c4*4+2] + a.w * xv[c4*4+3];
                ka[d] += bb.x * xv[c4*4+0] + bb.y * xv[c4*4+1] + bb.z * xv[c4*4+2] + bb.w * xv[c4*4+3];
            }
        }
    }
    float4* qo = (float4*)(qws + (size_t)g * D_);
    float4* ko = (float4*)(kws + (size_t)g * D_);
#pragma unroll
    for (int i = 0; i < 4; i++) {
        qo[i] = make_float4(qa[i*4+0], qa[i*4+1], qa[i*4+2], qa[i*4+3]);
        ko[i] = make_float4(ka[i*4+0], ka[i*4+1], ka[i*4+2], ka[i*4+3]);
    }
}

// ---------------- Kernel B: v projection ----------------
// v[b,o,j] = sum_c Wv[o,c] x[b,c,j] + bv[o]; stored as vws[b][j][o] (j-major)
// block 256, grid B * W/64 = 512
__global__ __launch_bounds__(256) void v_proj(
    const float* __restrict__ x, const float* __restrict__ Wv, const float* __restrict__ bv,
    float* __restrict__ vws)
{
    __shared__ float smem[64 * 129];  // 8256 floats; aliased: xs [128][64], outs [64][129]
    float (*xs)[64] = (float(*)[64])smem;

    int b  = blockIdx.x >> 6;
    int j0 = (blockIdx.x & 63) * 64;
    int tid = threadIdx.x;

    // stage x tile [c'][j] (32KB)
#pragma unroll
    for (int i = 0; i < 8; i++) {
        int f4 = tid + 256 * i;
        int row = f4 >> 4, col = (f4 & 15) * 4;
        *(float4*)&xs[row][col] = *(const float4*)(x + ((size_t)b * C_ + row) * W_ + j0 + col);
    }
    __syncthreads();

    int j  = tid & 63;
    int cg = tid >> 6;  // wave id (uniform): this wave's 32 output channels
    float acc[32];
#pragma unroll
    for (int i = 0; i < 32; i++) acc[i] = bv[cg * 32 + i];

    const float* wvb = Wv + (size_t)cg * 32 * C_;
    for (int c0 = 0; c0 < C_; c0 += 4) {
        float xv0 = xs[c0+0][j], xv1 = xs[c0+1][j], xv2 = xs[c0+2][j], xv3 = xs[c0+3][j];
#pragma unroll
        for (int i = 0; i < 32; i++) {
            float4 wv4 = *(const float4*)(wvb + i * C_ + c0);  // wave-uniform, L1 broadcast
            acc[i] += wv4.x * xv0 + wv4.y * xv1 + wv4.z * xv2 + wv4.w * xv3;
        }
    }
    __syncthreads();

    // transpose through LDS for coalesced store
    float (*outs)[129] = (float(*)[129])smem;
#pragma unroll
    for (int i = 0; i < 32; i++) outs[j][cg * 32 + i] = acc[i];
    __syncthreads();
#pragma unroll
    for (int i = 0; i < 8; i++) {
        int f4 = tid + 256 * i;
        int jj = f4 >> 5, c4 = (f4 & 31) * 4;
        float4 v;
        v.x = outs[jj][c4+0]; v.y = outs[jj][c4+1]; v.z = outs[jj][c4+2]; v.w = outs[jj][c4+3];
        *(float4*)(vws + ((size_t)b * W_ + j0 + jj) * C_ + c4) = v;
    }
}

// ---------------- Kernel C1: per-row softmax stats ----------------
// For each score row j: m2[j] = max_w s2[j,w], rl[j] = 1/sum_w exp2(s2-m2)
// block 256, grid 512; block handles 64 rows, scans all W keys in 64-tiles
__global__ __launch_bounds__(256) void row_stats(
    const float* __restrict__ qws, const float* __restrict__ kws,
    float* __restrict__ m2s, float* __restrict__ rls)
{
    __shared__ float ks[64][20];   // [w][d], stride 20 keeps float4 alignment
    __shared__ float mred[4][64];
    __shared__ float lred[4][64];

    int b  = blockIdx.x >> 6;
    int j0 = (blockIdx.x & 63) * 64;
    int tid = threadIdx.x;
    int jr = tid & 63, wg = tid >> 6;

    float q[16];
    {
        const float4* qp = (const float4*)(qws + ((size_t)b * W_ + j0 + jr) * D_);
#pragma unroll
        for (int i = 0; i < 4; i++) {
            float4 t = qp[i];
            q[i*4+0] = t.x; q[i*4+1] = t.y; q[i*4+2] = t.z; q[i*4+3] = t.w;
        }
    }

    float mt = -1e30f, lt = 0.0f;
    for (int t = 0; t < W_ / 64; t++) {
        int w0 = t * 64;
        __syncthreads();
        {
            int row = tid >> 2, dd = (tid & 3) * 4;
            *(float4*)&ks[row][dd] = *(const float4*)(kws + ((size_t)b * W_ + w0 + row) * D_ + dd);
        }
        __syncthreads();
#pragma unroll
        for (int ww = 0; ww < 16; ww++) {
            int w = wg * 16 + ww;
            float s = 0.0f;
#pragma unroll
            for (int d4 = 0; d4 < 4; d4++) {
                float4 k4 = *(const float4*)&ks[w][d4 * 4];
                s += k4.x * q[d4*4+0] + k4.y * q[d4*4+1] + k4.z * q[d4*4+2] + k4.w * q[d4*4+3];
            }
            s *= SCALE2;
            if (s <= mt) {
                lt += exp2f(s - mt);
            } else {
                lt = lt * exp2f(mt - s) + 1.0f;
                mt = s;
            }
        }
    }
    mred[wg][jr] = mt; lred[wg][jr] = lt;
    __syncthreads();
    if (tid < 64) {
        float m0 = mred[0][tid], m1 = mred[1][tid], m2 = mred[2][tid], m3 = mred[3][tid];
        float mm = fmaxf(fmaxf(m0, m1), fmaxf(m2, m3));
        float l = lred[0][tid] * exp2f(m0 - mm) + lred[1][tid] * exp2f(m1 - mm)
                + lred[2][tid] * exp2f(m2 - mm) + lred[3][tid] * exp2f(m3 - mm);
        m2s[(size_t)b * W_ + j0 + tid] = mm;
        rls[(size_t)b * W_ + j0 + tid] = 1.0f / l;
    }
}

// ---------------- Kernel C2: output accumulation ----------------
// out[b,c,w0+w] = x + sum_j exp2(s2[j,w]-m2[j])*rl[j] * v[b,j,c]
// block 256, grid 512; block owns 64 output columns (w), all 128 channels
__global__ __launch_bounds__(256) void attn_out(
    const float* __restrict__ x, const float* __restrict__ qws, const float* __restrict__ kws,
    const float* __restrict__ vws, const float* __restrict__ m2s, const float* __restrict__ rls,
    float* __restrict__ out)
{
    __shared__ float qs[64][20];
    __shared__ float vs[64][128];
    __shared__ float S[64][64];     // p values, [j][w]
    __shared__ float mrow[64], rrow[64];

    int b  = blockIdx.x >> 6;
    int w0 = (blockIdx.x & 63) * 64;
    int tid = threadIdx.x;
    int wl = tid & 63, jg = tid >> 6;

    float kr[16];
    {
        const float4* kp = (const float4*)(kws + ((size_t)b * W_ + w0 + wl) * D_);
#pragma unroll
        for (int i = 0; i < 4; i++) {
            float4 t = kp[i];
            kr[i*4+0] = t.x; kr[i*4+1] = t.y; kr[i*4+2] = t.z; kr[i*4+3] = t.w;
        }
    }

    float acc[8][4];
#pragma unroll
    for (int r = 0; r < 8; r++)
#pragma unroll
        for (int i = 0; i < 4; i++) acc[r][i] = 0.0f;

    int wg8  = tid & 7;   // w = wg8*8 + r
    int cgrp = tid >> 3;  // c = cgrp*4 + i

    for (int t = 0; t < W_ / 64; t++) {
        int j0 = t * 64;
        __syncthreads();
        {
            int row = tid >> 2, dd = (tid & 3) * 4;
            *(float4*)&qs[row][dd] = *(const float4*)(qws + ((size_t)b * W_ + j0 + row) * D_ + dd);
        }
#pragma unroll
        for (int i = 0; i < 8; i++) {
            int f4 = tid + 256 * i;
            int row = f4 >> 5, cc = (f4 & 31) * 4;
            *(float4*)&vs[row][cc] = *(const float4*)(vws + ((size_t)b * W_ + j0 + row) * C_ + cc);
        }
        if (tid < 64) {
            mrow[tid] = m2s[(size_t)b * W_ + j0 + tid];
            rrow[tid] = rls[(size_t)b * W_ + j0 + tid];
        }
        __syncthreads();

        // S phase: p[j, wl] for this block's 64 w-columns
#pragma unroll
        for (int jj = 0; jj < 16; jj++) {
            int j = jg * 16 + jj;
            float s = 0.0f;
#pragma unroll
            for (int d4 = 0; d4 < 4; d4++) {
                float4 q4 = *(const float4*)&qs[j][d4 * 4];
                s += q4.x * kr[d4*4+0] + q4.y * kr[d4*4+1] + q4.z * kr[d4*4+2] + q4.w * kr[d4*4+3];
            }
            S[j][wl] = exp2f(s * SCALE2 - mrow[j]) * rrow[j];
        }
        __syncthreads();

        // PV phase: 8w x 4c register tile per thread
        for (int j = 0; j < 64; j++) {
            float4 p0 = *(const float4*)&S[j][wg8 * 8];
            float4 p1 = *(const float4*)&S[j][wg8 * 8 + 4];
            float4 v4 = *(const float4*)&vs[j][cgrp * 4];
            float pr[8] = {p0.x, p0.y, p0.z, p0.w, p1.x, p1.y, p1.z, p1.w};
            float vv[4] = {v4.x, v4.y, v4.z, v4.w};
#pragma unroll
            for (int r = 0; r < 8; r++)
#pragma unroll
                for (int i = 0; i < 4; i++)
                    acc[r][i] = fmaf(pr[r], vv[i], acc[r][i]);
        }
    }

    // epilogue: + x, store
#pragma unroll
    for (int r = 0; r < 8; r++) {
        int w = w0 + wg8 * 8 + r;
#pragma unroll
        for (int i = 0; i < 4; i++) {
            int c = cgrp * 4 + i;
            size_t idx = ((size_t)b * C_ + c) * W_ + w;
            out[idx] = acc[r][i] + x[idx];
        }
    }
}

extern "C" void kernel_launch(void* const* d_in, const int* in_sizes, int n_in,
                              void* d_out, int out_size, void* d_ws, size_t ws_size,
                              hipStream_t stream)
{
    const float* x  = (const float*)d_in[0];
    const float* Wq = (const float*)d_in[1];
    const float* bq = (const float*)d_in[2];
    const float* Wk = (const float*)d_in[3];
    const float* bk = (const float*)d_in[4];
    const float* Wv = (const float*)d_in[5];
    const float* bv = (const float*)d_in[6];
    float* out = (float*)d_out;

    float* qws = (float*)d_ws;                       // [B][W][D]
    float* kws = qws + (size_t)B_ * W_ * D_;         // [B][W][D]
    float* vws = kws + (size_t)B_ * W_ * D_;         // [B][W][C]
    float* m2s = vws + (size_t)B_ * W_ * C_;         // [B][W]
    float* rls = m2s + (size_t)B_ * W_;              // [B][W]

    qk_proj<<<B_ * W_ / 128, 128, 0, stream>>>(x, Wq, bq, Wk, bk, qws, kws);
    v_proj<<<B_ * (W_ / 64), 256, 0, stream>>>(x, Wv, bv, vws);
    row_stats<<<B_ * (W_ / 64), 256, 0, stream>>>(qws, kws, m2s, rls);
    attn_out<<<B_ * (W_ / 64), 256, 0, stream>>>(x, qws, kws, vws, m2s, rls, out);
}

// Round 2
// 380.721 us; speedup vs baseline: 3.4840x; 3.4840x over previous
//
#include <hip/hip_runtime.h>

#define B_ 8
#define C_ 128
#define W_ 4096
#define D_ 16
// 0.25 (=D^-0.5) * log2(e): exp2 domain so exp -> v_exp_f32
#define SCALE2 0.3606737602222409f

typedef short bf16x8 __attribute__((ext_vector_type(8)));
typedef float f32x4 __attribute__((ext_vector_type(4)));

__device__ __forceinline__ unsigned short f2bf(float f) {
    unsigned int u = __float_as_uint(f);
    u += 0x7fffu + ((u >> 16) & 1u);
    return (unsigned short)(u >> 16);
}

// ---------------- Wv fp32 -> bf16 ----------------
__global__ __launch_bounds__(256) void wv_prep(const float* __restrict__ Wv, unsigned short* __restrict__ Wvbf) {
    int i = (blockIdx.x * 256 + threadIdx.x) * 4;
    float4 t = *(const float4*)(Wv + i);
    unsigned short h[4] = {f2bf(t.x), f2bf(t.y), f2bf(t.z), f2bf(t.w)};
    *(ushort4*)(Wvbf + i) = *(ushort4*)h;
}

// ---------------- q,k projection -> bf16 rows [pos][32] (d 16..31 zero) ----------------
// 65536 threads: first 32768 compute q, rest k. One thread per (b,w).
__global__ __launch_bounds__(256) void qk_proj(
    const float* __restrict__ x, const float* __restrict__ Wq, const float* __restrict__ bq,
    const float* __restrict__ Wk, const float* __restrict__ bk,
    unsigned short* __restrict__ qws, unsigned short* __restrict__ kws)
{
    int g = blockIdx.x * 256 + threadIdx.x;
    int isK = g >> 15;                    // block-uniform
    int p = g & 32767;
    int b = p >> 12, w = p & (W_ - 1);
    const float* Wm = isK ? Wk : Wq;
    const float* bm = isK ? bk : bq;
    unsigned short* outp = (isK ? kws : qws) + (size_t)p * 32;
    const float* xp = x + (size_t)b * C_ * W_ + w;

    float acc[16];
#pragma unroll
    for (int d = 0; d < 16; d++) acc[d] = bm[d];

    for (int c0 = 0; c0 < C_; c0 += 16) {
        float xv[16];
#pragma unroll
        for (int cc = 0; cc < 16; cc++) xv[cc] = xp[(size_t)(c0 + cc) * W_];
#pragma unroll
        for (int d = 0; d < 16; d++) {
            const float* wr = Wm + d * C_ + c0;
#pragma unroll
            for (int c4 = 0; c4 < 4; c4++) {
                float4 a = *(const float4*)(wr + c4 * 4);
                acc[d] += a.x * xv[c4*4+0] + a.y * xv[c4*4+1] + a.z * xv[c4*4+2] + a.w * xv[c4*4+3];
            }
        }
    }
    unsigned int u[8];
#pragma unroll
    for (int i = 0; i < 8; i++)
        u[i] = (unsigned int)f2bf(acc[2*i]) | ((unsigned int)f2bf(acc[2*i+1]) << 16);
    uint4* o4 = (uint4*)outp;
    o4[0] = make_uint4(u[0], u[1], u[2], u[3]);
    o4[1] = make_uint4(u[4], u[5], u[6], u[7]);
    o4[2] = make_uint4(0, 0, 0, 0);
    o4[3] = make_uint4(0, 0, 0, 0);
}

// ---------------- v projection (MFMA) -> bf16 [b][c][j] ----------------
__global__ __launch_bounds__(256) void v_proj(
    const float* __restrict__ x, const unsigned short* __restrict__ Wvbf,
    const float* __restrict__ bv, unsigned short* __restrict__ vws)
{
    __shared__ float xs[128][65];   // stride 65: <=2-way banks on column reads

    int b  = blockIdx.x >> 6;
    int j0 = (blockIdx.x & 63) * 64;
    int tid = threadIdx.x;
    int wid = tid >> 6, lane = tid & 63, n = lane & 15, q4 = lane >> 4;

    // stage x tile [c][j] fp32 (coalesced global reads)
#pragma unroll
    for (int i = 0; i < 8; i++) {
        int idx = tid + 256 * i;
        int row = idx >> 4, col = (idx & 15) * 4;
        float4 t = *(const float4*)(x + ((size_t)b * C_ + row) * W_ + j0 + col);
        xs[row][col+0] = t.x; xs[row][col+1] = t.y; xs[row][col+2] = t.z; xs[row][col+3] = t.w;
    }
    __syncthreads();

    f32x4 acc[2][4];
#pragma unroll
    for (int os = 0; os < 2; os++)
#pragma unroll
        for (int js = 0; js < 4; js++) acc[os][js] = (f32x4){0.f, 0.f, 0.f, 0.f};

    for (int kk = 0; kk < 128; kk += 32) {
        bf16x8 av[2];
#pragma unroll
        for (int os = 0; os < 2; os++) {
            int o = wid * 32 + os * 16 + n;
            av[os] = *(const bf16x8*)(Wvbf + (size_t)o * C_ + kk + q4 * 8);
        }
        bf16x8 bx[4];
#pragma unroll
        for (int js = 0; js < 4; js++) {
            int jl = js * 16 + n;
#pragma unroll
            for (int i = 0; i < 8; i++)
                bx[js][i] = (short)f2bf(xs[kk + q4 * 8 + i][jl]);
        }
#pragma unroll
        for (int os = 0; os < 2; os++)
#pragma unroll
            for (int js = 0; js < 4; js++)
                acc[os][js] = __builtin_amdgcn_mfma_f32_16x16x32_bf16(av[os], bx[js], acc[os][js], 0, 0, 0);
    }

#pragma unroll
    for (int os = 0; os < 2; os++) {
#pragma unroll
        for (int js = 0; js < 4; js++) {
#pragma unroll
            for (int r = 0; r < 4; r++) {
                int o = wid * 32 + os * 16 + q4 * 4 + r;
                int jj = j0 + js * 16 + n;
                vws[((size_t)b * C_ + o) * W_ + jj] = f2bf(acc[os][js][r] + bv[o]);
            }
        }
    }
}

// ---------------- row softmax stats (MFMA scores + online exp) ----------------
// m2s[j] = max_w s2[j,w], rls[j] = 1/sum_w exp2(s2-m2); j strip of 64 per block
__global__ __launch_bounds__(256) void row_stats(
    const unsigned short* __restrict__ qws, const unsigned short* __restrict__ kws,
    float* __restrict__ m2s, float* __restrict__ rls)
{
    int b  = blockIdx.x >> 6;
    int j0 = (blockIdx.x & 63) * 64;
    int tid = threadIdx.x;
    int wid = tid >> 6, lane = tid & 63, n = lane & 15, q4 = lane >> 4;

    bf16x8 aq = *(const bf16x8*)(qws + ((size_t)b * W_ + j0 + wid * 16 + n) * 32 + q4 * 8);
    const f32x4 zero = {0.f, 0.f, 0.f, 0.f};

    float mt[4], lt[4];
#pragma unroll
    for (int r = 0; r < 4; r++) { mt[r] = -1e30f; lt[r] = 0.f; }

    for (int w0 = 0; w0 < W_; w0 += 64) {
#pragma unroll
        for (int ws = 0; ws < 4; ws++) {
            bf16x8 bk = *(const bf16x8*)(kws + ((size_t)b * W_ + w0 + ws * 16 + n) * 32 + q4 * 8);
            f32x4 s4 = __builtin_amdgcn_mfma_f32_16x16x32_bf16(aq, bk, zero, 0, 0, 0);
#pragma unroll
            for (int r = 0; r < 4; r++) {
                float s = s4[r] * SCALE2;
                if (s <= mt[r]) {
                    lt[r] += exp2f(s - mt[r]);
                } else {
                    lt[r] = lt[r] * exp2f(mt[r] - s) + 1.0f;
                    mt[r] = s;
                }
            }
        }
    }

    // reduce across the 16 lanes of each quad (they hold disjoint w-columns)
#pragma unroll
    for (int mask = 1; mask < 16; mask <<= 1) {
#pragma unroll
        for (int r = 0; r < 4; r++) {
            float mo = __shfl_xor(mt[r], mask, 64);
            float lo = __shfl_xor(lt[r], mask, 64);
            float mm = fmaxf(mt[r], mo);
            lt[r] = lt[r] * exp2f(mt[r] - mm) + lo * exp2f(mo - mm);
            mt[r] = mm;
        }
    }
    if (n == 0) {
#pragma unroll
        for (int r = 0; r < 4; r++) {
            int j = j0 + wid * 16 + q4 * 4 + r;
            m2s[(size_t)b * W_ + j] = mt[r];
            rls[(size_t)b * W_ + j] = 1.0f / lt[r];
        }
    }
}

// ---------------- output: S via MFMA -> p -> LDS (xor-swizzled) -> PV MFMA ----------------
__global__ __launch_bounds__(256) void attn_out(
    const float* __restrict__ x, const unsigned short* __restrict__ qws,
    const unsigned short* __restrict__ kws, const unsigned short* __restrict__ vws,
    const float* __restrict__ m2s, const float* __restrict__ rls,
    float* __restrict__ out)
{
    __shared__ unsigned short pT[64 * 64];   // [w][j] bf16, chunk(16B) xor-swizzled by (w&7)
    __shared__ float mrow[64], rrow[64];

    int b  = blockIdx.x >> 6;
    int w0 = (blockIdx.x & 63) * 64;
    int tid = threadIdx.x;
    int wid = tid >> 6, lane = tid & 63, n = lane & 15, q4 = lane >> 4;

    // loop-invariant k fragments (B operand of S): 4 w-subtiles
    bf16x8 bk[4];
#pragma unroll
    for (int ws = 0; ws < 4; ws++)
        bk[ws] = *(const bf16x8*)(kws + ((size_t)b * W_ + w0 + ws * 16 + n) * 32 + q4 * 8);

    const f32x4 zero = {0.f, 0.f, 0.f, 0.f};
    f32x4 acc[2][4];
#pragma unroll
    for (int cs = 0; cs < 2; cs++)
#pragma unroll
        for (int ws = 0; ws < 4; ws++) acc[cs][ws] = zero;

    for (int jt = 0; jt < W_ / 64; jt++) {
        int j0 = jt * 64;
        if (tid < 64) {
            mrow[tid] = m2s[(size_t)b * W_ + j0 + tid];
            rrow[tid] = rls[(size_t)b * W_ + j0 + tid];
        }
        // S phase: wave wid computes j rows [wid*16, wid*16+16) x 64 w
        bf16x8 aq = *(const bf16x8*)(qws + ((size_t)b * W_ + j0 + wid * 16 + n) * 32 + q4 * 8);
        f32x4 s[4];
#pragma unroll
        for (int ws = 0; ws < 4; ws++)
            s[ws] = __builtin_amdgcn_mfma_f32_16x16x32_bf16(aq, bk[ws], zero, 0, 0, 0);

        __syncthreads();   // mrow ready; prev iteration's pT reads complete

        // p = exp2(s*SCALE2 - m)*rl -> swizzled pT[w][j]
#pragma unroll
        for (int ws = 0; ws < 4; ws++) {
            int w = ws * 16 + n;
#pragma unroll
            for (int rp = 0; rp < 2; rp++) {
                int jb = wid * 16 + q4 * 4 + 2 * rp;           // even
                float p0 = exp2f(s[ws][2*rp+0] * SCALE2 - mrow[jb+0]) * rrow[jb+0];
                float p1 = exp2f(s[ws][2*rp+1] * SCALE2 - mrow[jb+1]) * rrow[jb+1];
                int idx = w * 64 + (((jb >> 3) ^ (n & 7)) << 3) + (jb & 7);
                *(unsigned int*)&pT[idx] = (unsigned int)f2bf(p0) | ((unsigned int)f2bf(p1) << 16);
            }
        }
        __syncthreads();

        // PV: out[c 32 per wave][w 64] += v[c][j] * p[j][w], K=64 as 2 steps
#pragma unroll
        for (int kk = 0; kk < 64; kk += 32) {
            bf16x8 av[2];
#pragma unroll
            for (int cs = 0; cs < 2; cs++) {
                int c = wid * 32 + cs * 16 + n;
                av[cs] = *(const bf16x8*)(vws + ((size_t)b * C_ + c) * W_ + j0 + kk + q4 * 8);
            }
            bf16x8 bp[4];
#pragma unroll
            for (int ws = 0; ws < 4; ws++) {
                int w = ws * 16 + n;
                int cj = (kk >> 3) + q4;
                bp[ws] = *(const bf16x8*)&pT[w * 64 + ((cj ^ (n & 7)) << 3)];
            }
#pragma unroll
            for (int cs = 0; cs < 2; cs++)
#pragma unroll
                for (int ws = 0; ws < 4; ws++)
                    acc[cs][ws] = __builtin_amdgcn_mfma_f32_16x16x32_bf16(av[cs], bp[ws], acc[cs][ws], 0, 0, 0);
        }
    }

    // epilogue: + x
#pragma unroll
    for (int cs = 0; cs < 2; cs++) {
#pragma unroll
        for (int ws = 0; ws < 4; ws++) {
#pragma unroll
            for (int r = 0; r < 4; r++) {
                int c = wid * 32 + cs * 16 + q4 * 4 + r;
                int w = w0 + ws * 16 + n;
                size_t idx = ((size_t)b * C_ + c) * W_ + w;
                out[idx] = acc[cs][ws][r] + x[idx];
            }
        }
    }
}

extern "C" void kernel_launch(void* const* d_in, const int* in_sizes, int n_in,
                              void* d_out, int out_size, void* d_ws, size_t ws_size,
                              hipStream_t stream)
{
    const float* x  = (const float*)d_in[0];
    const float* Wq = (const float*)d_in[1];
    const float* bq = (const float*)d_in[2];
    const float* Wk = (const float*)d_in[3];
    const float* bk = (const float*)d_in[4];
    const float* Wv = (const float*)d_in[5];
    const float* bv = (const float*)d_in[6];
    float* out = (float*)d_out;

    unsigned short* qws = (unsigned short*)d_ws;                 // [B][W][32] bf16
    unsigned short* kws = qws + (size_t)B_ * W_ * 32;            // [B][W][32] bf16
    unsigned short* vws = kws + (size_t)B_ * W_ * 32;            // [B][C][W]  bf16
    unsigned short* wvb = vws + (size_t)B_ * C_ * W_;            // [C][C]     bf16
    float* m2s = (float*)(wvb + C_ * C_);                        // [B][W]
    float* rls = m2s + (size_t)B_ * W_;                          // [B][W]

    wv_prep<<<C_ * C_ / 1024, 256, 0, stream>>>(Wv, wvb);
    qk_proj<<<256, 256, 0, stream>>>(x, Wq, bq, Wk, bk, qws, kws);
    v_proj<<<B_ * (W_ / 64), 256, 0, stream>>>(x, wvb, bv, vws);
    row_stats<<<B_ * (W_ / 64), 256, 0, stream>>>(qws, kws, m2s, rls);
    attn_out<<<B_ * (W_ / 64), 256, 0, stream>>>(x, qws, kws, vws, m2s, rls, out);
}

// Round 3
// 204.971 us; speedup vs baseline: 6.4713x; 1.8574x over previous
//
#include <hip/hip_runtime.h>

#define B_ 8
#define C_ 128
#define W_ 4096
#define D_ 16
// D^-0.5 * log2(e): fold scale into Wq/bq; work in exp2 domain (v_exp_f32)
#define SCALE2 0.3606737602222409f

typedef short bf16x8 __attribute__((ext_vector_type(8)));
typedef float f32x4 __attribute__((ext_vector_type(4)));

__device__ __forceinline__ unsigned short f2bf(float f) {
    unsigned int u = __float_as_uint(f);
    u += 0x7fffu + ((u >> 16) & 1u);
    return (unsigned short)(u >> 16);
}
__device__ __forceinline__ float bf2f(unsigned short h) {
    return __uint_as_float(((unsigned int)h) << 16);
}
// LDS chunk swizzle: <=2-way banks for both transpose-writes and b128 reads
__device__ __forceinline__ int xswz(int j, int c8) {
    return c8 ^ (j & 7) ^ ((j >> 3) & 7);
}

// ---------------- prep: Wv -> bf16; [Wq*SCALE2 ; Wk] -> bf16 ----------------
// grid 20 x 256: groups 0..4095 Wv, 4096..4607 Wq, 4608..5119 Wk
__global__ __launch_bounds__(256) void prep(
    const float* __restrict__ Wq, const float* __restrict__ Wk, const float* __restrict__ Wv,
    unsigned short* __restrict__ Wvbf, unsigned short* __restrict__ Wqkbf)
{
    int g = blockIdx.x * 256 + threadIdx.x;
    const float* src; unsigned short* dst; float sc = 1.0f;
    if (g < 4096)      { src = Wv + g * 4;            dst = Wvbf + g * 4; }
    else if (g < 4608) { int t = g - 4096; src = Wq + t * 4; dst = Wqkbf + t * 4; sc = SCALE2; }
    else               { int t = g - 4608; src = Wk + t * 4; dst = Wqkbf + 2048 + t * 4; }
    float4 v = *(const float4*)src;
    unsigned short h[4] = {f2bf(v.x * sc), f2bf(v.y * sc), f2bf(v.z * sc), f2bf(v.w * sc)};
    *(ushort4*)dst = *(ushort4*)h;
}

// ---------------- proj: q,k,v in one pass (MFMA) ----------------
// qws/kws layout: [b][plane 0..3][pos][8] bf16 (plane p = k-dims 8p..8p+7; planes 2,3 zero)
// vws layout:     [b][c][W] bf16
__global__ __launch_bounds__(256) void proj(
    const float* __restrict__ x, const unsigned short* __restrict__ Wvbf,
    const unsigned short* __restrict__ Wqkbf,
    const float* __restrict__ bqp, const float* __restrict__ bkp, const float* __restrict__ bvp,
    unsigned short* __restrict__ qws, unsigned short* __restrict__ kws,
    unsigned short* __restrict__ vws)
{
    __shared__ unsigned short xbf[64 * 128];    // [j][c] swizzled chunks
    __shared__ unsigned short outs[128 * 72];   // v-store bounce, pad 72

    int b  = blockIdx.x & 7;
    int j0 = (blockIdx.x >> 3) * 64;
    int tid = threadIdx.x;
    int wid = tid >> 6, lane = tid & 63, n = lane & 15, q4 = lane >> 4;

    // stage x tile -> bf16 LDS [j][c], transposed, swizzled
#pragma unroll
    for (int i = 0; i < 8; i++) {
        int c = (tid >> 4) + 16 * i;
        int jc = (tid & 15) * 4;
        float4 t = *(const float4*)(x + (size_t)(b * C_ + c) * W_ + j0 + jc);
        float tv[4] = {t.x, t.y, t.z, t.w};
#pragma unroll
        for (int cc = 0; cc < 4; cc++) {
            int j = jc + cc;
            xbf[j * 128 + xswz(j, c >> 3) * 8 + (c & 7)] = f2bf(tv[cc]);
        }
    }
    __syncthreads();

    const f32x4 zero = {0.f, 0.f, 0.f, 0.f};
    f32x4 accv[2][4]; f32x4 accq = zero, acck = zero;
#pragma unroll
    for (int os = 0; os < 2; os++)
#pragma unroll
        for (int js = 0; js < 4; js++) accv[os][js] = zero;

#pragma unroll
    for (int kk = 0; kk < 128; kk += 32) {
        bf16x8 av[2], aqf, akf, bx[4];
#pragma unroll
        for (int os = 0; os < 2; os++)
            av[os] = *(const bf16x8*)(Wvbf + (wid * 32 + os * 16 + n) * 128 + kk + q4 * 8);
        aqf = *(const bf16x8*)(Wqkbf + n * 128 + kk + q4 * 8);
        akf = *(const bf16x8*)(Wqkbf + (16 + n) * 128 + kk + q4 * 8);
#pragma unroll
        for (int js = 0; js < 4; js++) {
            int j = js * 16 + n;
            bx[js] = *(const bf16x8*)&xbf[j * 128 + xswz(j, (kk >> 3) + q4) * 8];
        }
#pragma unroll
        for (int os = 0; os < 2; os++)
#pragma unroll
            for (int js = 0; js < 4; js++)
                accv[os][js] = __builtin_amdgcn_mfma_f32_16x16x32_bf16(av[os], bx[js], accv[os][js], 0, 0, 0);
        accq = __builtin_amdgcn_mfma_f32_16x16x32_bf16(aqf, bx[wid], accq, 0, 0, 0);
        acck = __builtin_amdgcn_mfma_f32_16x16x32_bf16(akf, bx[wid], acck, 0, 0, 0);
    }

    // q/k epilogue: rows d = q4*4+r, col j = n (wave's js = wid tile)
    {
        int pos = j0 + wid * 16 + n;
        float q0 = accq[0] + bqp[q4 * 4 + 0] * SCALE2;
        float q1 = accq[1] + bqp[q4 * 4 + 1] * SCALE2;
        float q2 = accq[2] + bqp[q4 * 4 + 2] * SCALE2;
        float q3 = accq[3] + bqp[q4 * 4 + 3] * SCALE2;
        float k0 = acck[0] + bkp[q4 * 4 + 0];
        float k1 = acck[1] + bkp[q4 * 4 + 1];
        float k2 = acck[2] + bkp[q4 * 4 + 2];
        float k3 = acck[3] + bkp[q4 * 4 + 3];
        size_t base = ((size_t)(b * 4 + (q4 >> 1)) * W_ + pos) * 8 + (q4 & 1) * 4;
        *(uint2*)(qws + base) = make_uint2((unsigned)f2bf(q0) | ((unsigned)f2bf(q1) << 16),
                                           (unsigned)f2bf(q2) | ((unsigned)f2bf(q3) << 16));
        *(uint2*)(kws + base) = make_uint2((unsigned)f2bf(k0) | ((unsigned)f2bf(k1) << 16),
                                           (unsigned)f2bf(k2) | ((unsigned)f2bf(k3) << 16));
    }
    // zero planes 2,3 of q/k (k-dims 16..31)
    {
        int which = tid >> 7;
        int plane = 2 + ((tid >> 6) & 1);
        int pos = j0 + (tid & 63);
        unsigned short* basep = which ? kws : qws;
        *(uint4*)(basep + ((size_t)(b * 4 + plane) * W_ + pos) * 8) = make_uint4(0, 0, 0, 0);
    }

    // v epilogue through LDS bounce for wide coalesced stores
    float bvv[2][4];
#pragma unroll
    for (int os = 0; os < 2; os++)
#pragma unroll
        for (int r = 0; r < 4; r++) bvv[os][r] = bvp[wid * 32 + os * 16 + q4 * 4 + r];
#pragma unroll
    for (int os = 0; os < 2; os++)
#pragma unroll
        for (int js = 0; js < 4; js++)
#pragma unroll
            for (int r = 0; r < 4; r++) {
                int c = wid * 32 + os * 16 + q4 * 4 + r;
                int j = js * 16 + n;
                outs[c * 72 + j] = f2bf(accv[os][js][r] + bvv[os][r]);
            }
    __syncthreads();
    {
        int c = tid >> 1, seg = tid & 1;
#pragma unroll
        for (int u = 0; u < 4; u++) {
            *(uint4*)(vws + (size_t)(b * C_ + c) * W_ + j0 + seg * 32 + u * 8) =
                *(const uint4*)&outs[c * 72 + seg * 32 + u * 8];
        }
    }
}

// ---------------- row_stats: rl[j] = 1 / sum_w exp2(s2[j,w]) (no max) ----------------
__global__ __launch_bounds__(256) void row_stats(
    const unsigned short* __restrict__ qws, const unsigned short* __restrict__ kws,
    float* __restrict__ rls)
{
    int b  = blockIdx.x & 7;
    int j0 = (blockIdx.x >> 3) * 64;
    int tid = threadIdx.x;
    int wid = tid >> 6, lane = tid & 63, n = lane & 15, q4 = lane >> 4;

    const bf16x8* qbase = (const bf16x8*)qws + (size_t)(b * 4 + q4) * W_;
    const bf16x8* kbase = (const bf16x8*)kws + (size_t)(b * 4 + q4) * W_;
    bf16x8 aq = qbase[j0 + wid * 16 + n];
    const f32x4 zero = {0.f, 0.f, 0.f, 0.f};

    float lt[4] = {0.f, 0.f, 0.f, 0.f};
    bf16x8 bkc[4];
#pragma unroll
    for (int ws = 0; ws < 4; ws++) bkc[ws] = kbase[ws * 16 + n];

    for (int t = 0; t < W_ / 64; t++) {
        f32x4 s[4];
#pragma unroll
        for (int ws = 0; ws < 4; ws++)
            s[ws] = __builtin_amdgcn_mfma_f32_16x16x32_bf16(aq, bkc[ws], zero, 0, 0, 0);
        int tn = (t + 1) & 63;  // branchless prefetch (wraps, harmless)
#pragma unroll
        for (int ws = 0; ws < 4; ws++) bkc[ws] = kbase[tn * 64 + ws * 16 + n];
#pragma unroll
        for (int ws = 0; ws < 4; ws++)
#pragma unroll
            for (int r = 0; r < 4; r++) lt[r] += exp2f(s[ws][r]);
    }
    // sum over the 16 lanes (w-columns) of each quad-row group
#pragma unroll
    for (int mask = 1; mask < 16; mask <<= 1)
#pragma unroll
        for (int r = 0; r < 4; r++) lt[r] += __shfl_xor(lt[r], mask, 64);
    if (n == 0) {
        f32x4 rl = {1.f / lt[0], 1.f / lt[1], 1.f / lt[2], 1.f / lt[3]};
        *(f32x4*)(rls + (size_t)b * W_ + j0 + wid * 16 + q4 * 4) = rl;
    }
}

// ---------------- vscale: v'[c,j] = v[c,j] * rl[j] (in-place) ----------------
__global__ __launch_bounds__(256) void vscale(unsigned short* __restrict__ vws,
                                              const float* __restrict__ rls)
{
    int g = blockIdx.x * 256 + threadIdx.x;      // 524288 threads, 8 bf16 each
    size_t f0 = (size_t)g * 8;
    int b = (int)(f0 >> 19);
    int j = (int)(f0 & (W_ - 1));
    const float* rp = rls + (size_t)b * W_ + j;
    uint4 v = *(const uint4*)(vws + f0);
    unsigned int wv[4] = {v.x, v.y, v.z, v.w};
    unsigned int o[4];
#pragma unroll
    for (int u = 0; u < 4; u++) {
        float lo = bf2f((unsigned short)(wv[u] & 0xffffu)) * rp[2 * u];
        float hi = bf2f((unsigned short)(wv[u] >> 16)) * rp[2 * u + 1];
        o[u] = (unsigned)f2bf(lo) | ((unsigned)f2bf(hi) << 16);
    }
    *(uint4*)(vws + f0) = make_uint4(o[0], o[1], o[2], o[3]);
}

// ---------------- attn_out: S MFMA -> exp2 -> pT (dbuf, 1 sync/tile) -> PV MFMA ----------------
__global__ __launch_bounds__(256, 2) void attn_out(
    const float* __restrict__ x, const unsigned short* __restrict__ qws,
    const unsigned short* __restrict__ kws, const unsigned short* __restrict__ vws,
    float* __restrict__ out)
{
    __shared__ unsigned short pT[2][64 * 64];   // [w][j] bf16, chunk xor-swizzled by w&7

    int b  = blockIdx.x & 7;
    int w0 = (blockIdx.x >> 3) * 64;
    int tid = threadIdx.x;
    int wid = tid >> 6, lane = tid & 63, n = lane & 15, q4 = lane >> 4;

    const bf16x8* qbase = (const bf16x8*)qws + (size_t)(b * 4 + q4) * W_;
    const bf16x8* kbase = (const bf16x8*)kws + (size_t)(b * 4 + q4) * W_;
    const bf16x8* vbase = (const bf16x8*)vws;

    bf16x8 bk[4];
#pragma unroll
    for (int ws = 0; ws < 4; ws++) bk[ws] = kbase[w0 + ws * 16 + n];

    const f32x4 zero = {0.f, 0.f, 0.f, 0.f};
    f32x4 acc[2][4];
#pragma unroll
    for (int cs = 0; cs < 2; cs++)
#pragma unroll
        for (int ws = 0; ws < 4; ws++) acc[cs][ws] = zero;

    bf16x8 aq_c = qbase[wid * 16 + n];
    bf16x8 av_c[2][2];
#pragma unroll
    for (int cs = 0; cs < 2; cs++)
#pragma unroll
        for (int kh = 0; kh < 2; kh++)
            av_c[cs][kh] = vbase[(size_t)(b * C_ + wid * 32 + cs * 16 + n) * 512 + kh * 4 + q4];

    int buf = 0;
    for (int jt = 0; jt < W_ / 64; jt++) {
        f32x4 s[4];
#pragma unroll
        for (int ws = 0; ws < 4; ws++)
            s[ws] = __builtin_amdgcn_mfma_f32_16x16x32_bf16(aq_c, bk[ws], zero, 0, 0, 0);

        // prefetch next tile (branchless wrap) — hidden under exp2/pack
        int jn = (jt + 1) & 63;
        bf16x8 aq_n = qbase[jn * 16 * 4 + wid * 16 + n];
        bf16x8 av_n[2][2];
#pragma unroll
        for (int cs = 0; cs < 2; cs++)
#pragma unroll
            for (int kh = 0; kh < 2; kh++)
                av_n[cs][kh] = vbase[(size_t)(b * C_ + wid * 32 + cs * 16 + n) * 512 + jn * 8 + kh * 4 + q4];

        // p = exp2(s) (rl pre-folded into v'), pack bf16 pairs, swizzled store
#pragma unroll
        for (int ws = 0; ws < 4; ws++) {
            int w = ws * 16 + n;
#pragma unroll
            for (int rp = 0; rp < 2; rp++) {
                int jb = wid * 16 + q4 * 4 + 2 * rp;
                float p0 = exp2f(s[ws][2 * rp + 0]);
                float p1 = exp2f(s[ws][2 * rp + 1]);
                int idx = w * 64 + (((jb >> 3) ^ (n & 7)) << 3) + (jb & 7);
                *(unsigned int*)&pT[buf][idx] = (unsigned)f2bf(p0) | ((unsigned)f2bf(p1) << 16);
            }
        }
        __syncthreads();

        // PV: out[c][w] += v'[c][j] * p[j][w]
#pragma unroll
        for (int kh = 0; kh < 2; kh++) {
            bf16x8 bp[4];
#pragma unroll
            for (int ws = 0; ws < 4; ws++) {
                int w = ws * 16 + n;
                int cj = kh * 4 + q4;
                bp[ws] = *(const bf16x8*)&pT[buf][w * 64 + ((cj ^ (n & 7)) << 3)];
            }
#pragma unroll
            for (int cs = 0; cs < 2; cs++)
#pragma unroll
                for (int ws = 0; ws < 4; ws++)
                    acc[cs][ws] = __builtin_amdgcn_mfma_f32_16x16x32_bf16(av_c[cs][kh], bp[ws], acc[cs][ws], 0, 0, 0);
        }

        aq_c = aq_n;
#pragma unroll
        for (int cs = 0; cs < 2; cs++)
#pragma unroll
            for (int kh = 0; kh < 2; kh++) av_c[cs][kh] = av_n[cs][kh];
        buf ^= 1;
    }

    // epilogue: + x
#pragma unroll
    for (int cs = 0; cs < 2; cs++)
#pragma unroll
        for (int ws = 0; ws < 4; ws++)
#pragma unroll
            for (int r = 0; r < 4; r++) {
                int c = wid * 32 + cs * 16 + q4 * 4 + r;
                int w = w0 + ws * 16 + n;
                size_t idx = (size_t)(b * C_ + c) * W_ + w;
                out[idx] = acc[cs][ws][r] + x[idx];
            }
}

extern "C" void kernel_launch(void* const* d_in, const int* in_sizes, int n_in,
                              void* d_out, int out_size, void* d_ws, size_t ws_size,
                              hipStream_t stream)
{
    const float* x  = (const float*)d_in[0];
    const float* Wq = (const float*)d_in[1];
    const float* bq = (const float*)d_in[2];
    const float* Wk = (const float*)d_in[3];
    const float* bk = (const float*)d_in[4];
    const float* Wv = (const float*)d_in[5];
    const float* bv = (const float*)d_in[6];
    float* out = (float*)d_out;

    unsigned short* qws  = (unsigned short*)d_ws;        // [B][4][W][8] bf16 = 2MB
    unsigned short* kws  = qws + (size_t)1048576;        // [B][4][W][8] bf16 = 2MB
    unsigned short* vws  = kws + (size_t)1048576;        // [B][C][W] bf16 = 8MB
    unsigned short* Wvbf = vws + (size_t)4194304;        // [128][128]
    unsigned short* Wqkbf = Wvbf + 16384;                // [32][128] (q rows scaled)
    float* rls = (float*)(Wqkbf + 4096);                 // [B][W]

    prep<<<20, 256, 0, stream>>>(Wq, Wk, Wv, Wvbf, Wqkbf);
    proj<<<512, 256, 0, stream>>>(x, Wvbf, Wqkbf, bq, bk, bv, qws, kws, vws);
    row_stats<<<512, 256, 0, stream>>>(qws, kws, rls);
    vscale<<<2048, 256, 0, stream>>>(vws, rls);
    attn_out<<<512, 256, 0, stream>>>(x, qws, kws, vws, out);
}

// Round 4
// 167.888 us; speedup vs baseline: 7.9006x; 1.2209x over previous
//
#include <hip/hip_runtime.h>

#define B_ 8
#define C_ 128
#define W_ 4096
#define D_ 16
// D^-0.5 * log2(e): folded into Wq/bq; exp2 domain (v_exp_f32)
#define SCALE2 0.3606737602222409f

typedef short bf16x8 __attribute__((ext_vector_type(8)));
typedef float f32x4 __attribute__((ext_vector_type(4)));

__device__ __forceinline__ unsigned short f2bf(float f) {
    unsigned int u = __float_as_uint(f);
    u += 0x7fffu + ((u >> 16) & 1u);
    return (unsigned short)(u >> 16);
}
// pack two f32 -> u32 of 2 bf16 (TRUNCATED) in ONE v_perm_b32
__device__ __forceinline__ unsigned int pk2bf(float lo, float hi) {
    return __builtin_amdgcn_perm(__float_as_uint(hi), __float_as_uint(lo), 0x07060302u);
}
__device__ __forceinline__ bf16x8 u4_to_bf8(unsigned int a, unsigned int b,
                                            unsigned int c, unsigned int d) {
    union { uint4 u; bf16x8 v; } t;
    t.u = make_uint4(a, b, c, d);
    return t.v;
}
// LDS chunk swizzle for proj staging: <=2-way banks both directions
__device__ __forceinline__ int xswz(int j, int c8) {
    return c8 ^ (j & 7) ^ ((j >> 3) & 7);
}

// ---------------- prep: Wv -> bf16; [Wq*SCALE2 ; Wk] -> bf16 ----------------
__global__ __launch_bounds__(256) void prep(
    const float* __restrict__ Wq, const float* __restrict__ Wk, const float* __restrict__ Wv,
    unsigned short* __restrict__ Wvbf, unsigned short* __restrict__ Wqkbf)
{
    int g = blockIdx.x * 256 + threadIdx.x;
    const float* src; unsigned short* dst; float sc = 1.0f;
    if (g < 4096)      { src = Wv + g * 4;            dst = Wvbf + g * 4; }
    else if (g < 4608) { int t = g - 4096; src = Wq + t * 4; dst = Wqkbf + t * 4; sc = SCALE2; }
    else               { int t = g - 4608; src = Wk + t * 4; dst = Wqkbf + 2048 + t * 4; }
    float4 v = *(const float4*)src;
    unsigned short h[4] = {f2bf(v.x * sc), f2bf(v.y * sc), f2bf(v.z * sc), f2bf(v.w * sc)};
    *(ushort4*)dst = *(ushort4*)h;
}

// ---------------- proj: q,k,v in one pass (MFMA) ----------------
// qws/kws: [b][plane 0..3][pos][8] bf16. plane2 of k = {1.0,0...}; plane2 of q
// zeroed here, dim16 slot later filled with log2(1/l) by row_stats. plane3 = 0.
// vws: j-tiled [b][j/16][c][j%16] bf16 (coalesced stores here + frag loads in attn_out)
__global__ __launch_bounds__(256) void proj(
    const float* __restrict__ x, const unsigned short* __restrict__ Wvbf,
    const unsigned short* __restrict__ Wqkbf,
    const float* __restrict__ bqp, const float* __restrict__ bkp, const float* __restrict__ bvp,
    unsigned short* __restrict__ qws, unsigned short* __restrict__ kws,
    unsigned short* __restrict__ vws)
{
    __shared__ unsigned short xbf[64 * 128];    // [j][c] swizzled chunks
    __shared__ unsigned short outs[128 * 72];   // v-store bounce, pad 72

    int b  = blockIdx.x & 7;
    int j0 = (blockIdx.x >> 3) * 64;
    int tid = threadIdx.x;
    int wid = tid >> 6, lane = tid & 63, n = lane & 15, q4 = lane >> 4;

#pragma unroll
    for (int i = 0; i < 8; i++) {
        int c = (tid >> 4) + 16 * i;
        int jc = (tid & 15) * 4;
        float4 t = *(const float4*)(x + (size_t)(b * C_ + c) * W_ + j0 + jc);
        float tv[4] = {t.x, t.y, t.z, t.w};
#pragma unroll
        for (int cc = 0; cc < 4; cc++) {
            int j = jc + cc;
            xbf[j * 128 + xswz(j, c >> 3) * 8 + (c & 7)] = f2bf(tv[cc]);
        }
    }
    __syncthreads();

    const f32x4 zero = {0.f, 0.f, 0.f, 0.f};
    f32x4 accv[2][4]; f32x4 accq = zero, acck = zero;
#pragma unroll
    for (int os = 0; os < 2; os++)
#pragma unroll
        for (int js = 0; js < 4; js++) accv[os][js] = zero;

#pragma unroll
    for (int kk = 0; kk < 128; kk += 32) {
        bf16x8 av[2], aqf, akf, bx[4];
#pragma unroll
        for (int os = 0; os < 2; os++)
            av[os] = *(const bf16x8*)(Wvbf + (wid * 32 + os * 16 + n) * 128 + kk + q4 * 8);
        aqf = *(const bf16x8*)(Wqkbf + n * 128 + kk + q4 * 8);
        akf = *(const bf16x8*)(Wqkbf + (16 + n) * 128 + kk + q4 * 8);
#pragma unroll
        for (int js = 0; js < 4; js++) {
            int j = js * 16 + n;
            bx[js] = *(const bf16x8*)&xbf[j * 128 + xswz(j, (kk >> 3) + q4) * 8];
        }
#pragma unroll
        for (int os = 0; os < 2; os++)
#pragma unroll
            for (int js = 0; js < 4; js++)
                accv[os][js] = __builtin_amdgcn_mfma_f32_16x16x32_bf16(av[os], bx[js], accv[os][js], 0, 0, 0);
        accq = __builtin_amdgcn_mfma_f32_16x16x32_bf16(aqf, bx[wid], accq, 0, 0, 0);
        acck = __builtin_amdgcn_mfma_f32_16x16x32_bf16(akf, bx[wid], acck, 0, 0, 0);
    }

    // q/k epilogue
    {
        int pos = j0 + wid * 16 + n;
        float q0 = accq[0] + bqp[q4 * 4 + 0] * SCALE2;
        float q1 = accq[1] + bqp[q4 * 4 + 1] * SCALE2;
        float q2 = accq[2] + bqp[q4 * 4 + 2] * SCALE2;
        float q3 = accq[3] + bqp[q4 * 4 + 3] * SCALE2;
        float k0 = acck[0] + bkp[q4 * 4 + 0];
        float k1 = acck[1] + bkp[q4 * 4 + 1];
        float k2 = acck[2] + bkp[q4 * 4 + 2];
        float k3 = acck[3] + bkp[q4 * 4 + 3];
        size_t base = ((size_t)(b * 4 + (q4 >> 1)) * W_ + pos) * 8 + (q4 & 1) * 4;
        *(uint2*)(qws + base) = make_uint2((unsigned)f2bf(q0) | ((unsigned)f2bf(q1) << 16),
                                           (unsigned)f2bf(q2) | ((unsigned)f2bf(q3) << 16));
        *(uint2*)(kws + base) = make_uint2((unsigned)f2bf(k0) | ((unsigned)f2bf(k1) << 16),
                                           (unsigned)f2bf(k2) | ((unsigned)f2bf(k3) << 16));
    }
    // planes 2,3: zero, except k plane2 dim16 = 1.0 (bf16 0x3f80)
    {
        int which = tid >> 7;
        int plane = 2 + ((tid >> 6) & 1);
        int pos = j0 + (tid & 63);
        unsigned short* basep = which ? kws : qws;
        uint4 z = make_uint4(0, 0, 0, 0);
        if (which == 1 && plane == 2) z.x = 0x3f80u;
        *(uint4*)(basep + ((size_t)(b * 4 + plane) * W_ + pos) * 8) = z;
    }

    // v epilogue -> LDS bounce -> j-tiled layout
    float bvv[2][4];
#pragma unroll
    for (int os = 0; os < 2; os++)
#pragma unroll
        for (int r = 0; r < 4; r++) bvv[os][r] = bvp[wid * 32 + os * 16 + q4 * 4 + r];
#pragma unroll
    for (int os = 0; os < 2; os++)
#pragma unroll
        for (int js = 0; js < 4; js++)
#pragma unroll
            for (int r = 0; r < 4; r++) {
                int c = wid * 32 + os * 16 + q4 * 4 + r;
                int j = js * 16 + n;
                outs[c * 72 + j] = f2bf(accv[os][js][r] + bvv[os][r]);
            }
    __syncthreads();
    {
        int p = tid;
#pragma unroll
        for (int rep = 0; rep < 2; rep++, p += 256) {
            int jt_l = p >> 7;          // 0..3
            int c    = p & 127;
            const uint4* src = (const uint4*)&outs[c * 72 + jt_l * 16];
            unsigned short* dst = vws + ((size_t)((b * 256 + (j0 >> 4) + jt_l) * 128 + c)) * 16;
            *(uint4*)(dst + 0) = src[0];
            *(uint4*)(dst + 8) = src[1];
        }
    }
}

// ---------------- row_stats: q plane2 dim16 <- -log2( sum_w exp2(q.k) ) ----------------
__global__ __launch_bounds__(256) void row_stats(
    unsigned short* __restrict__ qws, const unsigned short* __restrict__ kws)
{
    int b  = blockIdx.x & 7;
    int j0 = (blockIdx.x >> 3) * 64;
    int tid = threadIdx.x;
    int wid = tid >> 6, lane = tid & 63, n = lane & 15, q4 = lane >> 4;

    const bf16x8* qbase = (const bf16x8*)qws + (size_t)(b * 4 + q4) * W_;
    const bf16x8* kbase = (const bf16x8*)kws + (size_t)(b * 4 + q4) * W_;
    bf16x8 aq = qbase[j0 + wid * 16 + n];
    const f32x4 zero = {0.f, 0.f, 0.f, 0.f};

    float lt[4] = {0.f, 0.f, 0.f, 0.f};
    bf16x8 bkc[4];
#pragma unroll
    for (int ws = 0; ws < 4; ws++) bkc[ws] = kbase[ws * 16 + n];

    for (int t = 0; t < W_ / 64; t++) {
        f32x4 s[4];
#pragma unroll
        for (int ws = 0; ws < 4; ws++)
            s[ws] = __builtin_amdgcn_mfma_f32_16x16x32_bf16(aq, bkc[ws], zero, 0, 0, 0);
        int tn = (t + 1) & 63;  // branchless prefetch (wraps, harmless)
#pragma unroll
        for (int ws = 0; ws < 4; ws++) bkc[ws] = kbase[tn * 64 + ws * 16 + n];
#pragma unroll
        for (int ws = 0; ws < 4; ws++)
#pragma unroll
            for (int r = 0; r < 4; r++) lt[r] += __builtin_amdgcn_exp2f(s[ws][r]);
    }
#pragma unroll
    for (int mask = 1; mask < 16; mask <<= 1)
#pragma unroll
        for (int r = 0; r < 4; r++) lt[r] += __shfl_xor(lt[r], mask, 64);
    if (n == 0) {
#pragma unroll
        for (int r = 0; r < 4; r++) {
            int j = j0 + wid * 16 + q4 * 4 + r;
            qws[((size_t)(b * 4 + 2) * W_ + j) * 8] = f2bf(-__builtin_amdgcn_logf(lt[r]));
        }
    }
}

// ---------------- attn_out: barrier-free K-loop, wave-private P ----------------
// Each wave owns j-slice {it*128 + wid*16 .. +16, +64..} ; covers ALL 128 c x 64 w.
// S C-layout IS the PV B-fragment under the k-slot<->j bijection (see analysis).
// Cross-wave j-reduction via LDS once at the end.
__global__ __launch_bounds__(256, 2) void attn_out(
    const float* __restrict__ x, const unsigned short* __restrict__ qws,
    const unsigned short* __restrict__ kws, const unsigned short* __restrict__ vws,
    float* __restrict__ out)
{
    __shared__ float red[2][128 * 68];   // 69.6 KB: reduction + store bounce

    int b  = blockIdx.x & 7;
    int w0 = (blockIdx.x >> 3) * 64;
    int tid = threadIdx.x;
    int wid = tid >> 6, lane = tid & 63, n = lane & 15, q4 = lane >> 4;

    const bf16x8* qbase = (const bf16x8*)qws + (size_t)(b * 4 + q4) * W_;
    const bf16x8* kbase = (const bf16x8*)kws + (size_t)(b * 4 + q4) * W_;
    const unsigned short* vtb = vws + (size_t)b * 256 * 128 * 16;

    bf16x8 bk[4];
#pragma unroll
    for (int ws = 0; ws < 4; ws++) bk[ws] = kbase[w0 + ws * 16 + n];

    const f32x4 zero = {0.f, 0.f, 0.f, 0.f};
    f32x4 acc[8][4];   // [mt(c)][nt(w)]
#pragma unroll
    for (int mt = 0; mt < 8; mt++)
#pragma unroll
        for (int nt = 0; nt < 4; nt++) acc[mt][nt] = zero;

    bf16x8 aqA = qbase[wid * 16 + n];
    bf16x8 aqB = qbase[64 + wid * 16 + n];

    for (int it = 0; it < 32; it++) {
        f32x4 sA[4], sB[4];
#pragma unroll
        for (int ws = 0; ws < 4; ws++) {
            sA[ws] = __builtin_amdgcn_mfma_f32_16x16x32_bf16(aqA, bk[ws], zero, 0, 0, 0);
            sB[ws] = __builtin_amdgcn_mfma_f32_16x16x32_bf16(aqB, bk[ws], zero, 0, 0, 0);
        }
        // prefetch next iter's q frags (no barrier anywhere to drain them)
        int itn = (it + 1) & 31;
        bf16x8 aqA_n = qbase[itn * 128 + wid * 16 + n];
        bf16x8 aqB_n = qbase[itn * 128 + 64 + wid * 16 + n];

        // p = exp2(s) (log2(1/l) rides in q plane2 * k plane2); trunc-pack via v_perm
        bf16x8 bfrag[4];
#pragma unroll
        for (int ws = 0; ws < 4; ws++) {
            float pA0 = __builtin_amdgcn_exp2f(sA[ws][0]);
            float pA1 = __builtin_amdgcn_exp2f(sA[ws][1]);
            float pA2 = __builtin_amdgcn_exp2f(sA[ws][2]);
            float pA3 = __builtin_amdgcn_exp2f(sA[ws][3]);
            float pB0 = __builtin_amdgcn_exp2f(sB[ws][0]);
            float pB1 = __builtin_amdgcn_exp2f(sB[ws][1]);
            float pB2 = __builtin_amdgcn_exp2f(sB[ws][2]);
            float pB3 = __builtin_amdgcn_exp2f(sB[ws][3]);
            bfrag[ws] = u4_to_bf8(pk2bf(pA0, pA1), pk2bf(pA2, pA3),
                                  pk2bf(pB0, pB1), pk2bf(pB2, pB3));
        }

        // PV: A = v fragments with the same k-slot<->j bijection
        int jtA = it * 8 + wid;       // (it*128 + wid*16)/16
        int jtB = jtA + 4;
#pragma unroll
        for (int mt = 0; mt < 8; mt++) {
            int c = mt * 16 + n;
            uint2 a0 = *(const uint2*)(vtb + (size_t)(jtA * 128 + c) * 16 + q4 * 4);
            uint2 a1 = *(const uint2*)(vtb + (size_t)(jtB * 128 + c) * 16 + q4 * 4);
            bf16x8 af = u4_to_bf8(a0.x, a0.y, a1.x, a1.y);
#pragma unroll
            for (int nt = 0; nt < 4; nt++)
                acc[mt][nt] = __builtin_amdgcn_mfma_f32_16x16x32_bf16(af, bfrag[nt], acc[mt][nt], 0, 0, 0);
        }
        aqA = aqA_n; aqB = aqB_n;
    }

    // ---- cross-wave reduction: waves 2,3 -> bufs; 0+=red0? (0<-2, 1<-3); 1 -> buf0; 0+= ; store
#pragma unroll 1
    for (int step = 0; step < 1; step++) {}   // (no-op; keeps structure flat)

    if (wid >= 2) {
        float* buf = red[wid - 2];
#pragma unroll
        for (int mt = 0; mt < 8; mt++)
#pragma unroll
            for (int nt = 0; nt < 4; nt++)
#pragma unroll
                for (int r = 0; r < 4; r++)
                    buf[(mt * 16 + q4 * 4 + r) * 68 + nt * 16 + n] = acc[mt][nt][r];
    }
    __syncthreads();
    if (wid < 2) {
        const float* buf = red[wid];
#pragma unroll
        for (int mt = 0; mt < 8; mt++)
#pragma unroll
            for (int nt = 0; nt < 4; nt++)
#pragma unroll
                for (int r = 0; r < 4; r++)
                    acc[mt][nt][r] += buf[(mt * 16 + q4 * 4 + r) * 68 + nt * 16 + n];
    }
    __syncthreads();
    if (wid == 1) {
        float* buf = red[0];
#pragma unroll
        for (int mt = 0; mt < 8; mt++)
#pragma unroll
            for (int nt = 0; nt < 4; nt++)
#pragma unroll
                for (int r = 0; r < 4; r++)
                    buf[(mt * 16 + q4 * 4 + r) * 68 + nt * 16 + n] = acc[mt][nt][r];
    }
    __syncthreads();
    if (wid == 0) {
        float* buf = red[0];
#pragma unroll
        for (int mt = 0; mt < 8; mt++)
#pragma unroll
            for (int nt = 0; nt < 4; nt++)
#pragma unroll
                for (int r = 0; r < 4; r++) {
                    int idx = (mt * 16 + q4 * 4 + r) * 68 + nt * 16 + n;
                    buf[idx] = acc[mt][nt][r] + buf[idx];
                }
    }
    __syncthreads();
    // coalesced store: out = red[0] + x
    {
#pragma unroll
        for (int u = 0; u < 8; u++) {
            int k = tid + 256 * u;          // 2048 float4 slots
            int c = k >> 4, wseg = (k & 15) * 4;
            size_t gidx = (size_t)(b * C_ + c) * W_ + w0 + wseg;
            float4 xv = *(const float4*)(x + gidx);
            const float* s = &red[0][c * 68 + wseg];
            float4 o = make_float4(s[0] + xv.x, s[1] + xv.y, s[2] + xv.z, s[3] + xv.w);
            *(float4*)(out + gidx) = o;
        }
    }
}

extern "C" void kernel_launch(void* const* d_in, const int* in_sizes, int n_in,
                              void* d_out, int out_size, void* d_ws, size_t ws_size,
                              hipStream_t stream)
{
    const float* x  = (const float*)d_in[0];
    const float* Wq = (const float*)d_in[1];
    const float* bq = (const float*)d_in[2];
    const float* Wk = (const float*)d_in[3];
    const float* bk = (const float*)d_in[4];
    const float* Wv = (const float*)d_in[5];
    const float* bv = (const float*)d_in[6];
    float* out = (float*)d_out;

    unsigned short* qws  = (unsigned short*)d_ws;        // [B][4][W][8] bf16 = 2MB
    unsigned short* kws  = qws + (size_t)1048576;        // [B][4][W][8] bf16 = 2MB
    unsigned short* vws  = kws + (size_t)1048576;        // [B][W/16][C][16] bf16 = 8MB
    unsigned short* Wvbf = vws + (size_t)4194304;        // [128][128]
    unsigned short* Wqkbf = Wvbf + 16384;                // [32][128] (q rows pre-scaled)

    prep<<<20, 256, 0, stream>>>(Wq, Wk, Wv, Wvbf, Wqkbf);
    proj<<<512, 256, 0, stream>>>(x, Wvbf, Wqkbf, bq, bk, bv, qws, kws, vws);
    row_stats<<<512, 256, 0, stream>>>(qws, kws);
    attn_out<<<512, 256, 0, stream>>>(x, qws, kws, vws, out);
}

// Round 5
// 167.309 us; speedup vs baseline: 7.9280x; 1.0035x over previous
//
#include <hip/hip_runtime.h>

#define B_ 8
#define C_ 128
#define W_ 4096
#define D_ 16
// D^-0.5 * log2(e): folded into Wq/bq; exp2 domain (v_exp_f32)
#define SCALE2 0.3606737602222409f

typedef short bf16x8 __attribute__((ext_vector_type(8)));
typedef float f32x4 __attribute__((ext_vector_type(4)));

__device__ __forceinline__ unsigned short f2bf(float f) {
    unsigned int u = __float_as_uint(f);
    u += 0x7fffu + ((u >> 16) & 1u);
    return (unsigned short)(u >> 16);
}
// pack two f32 -> u32 of 2 bf16 (TRUNCATED) in ONE v_perm_b32
__device__ __forceinline__ unsigned int pk2bf(float lo, float hi) {
    return __builtin_amdgcn_perm(__float_as_uint(hi), __float_as_uint(lo), 0x07060302u);
}
__device__ __forceinline__ bf16x8 u4_to_bf8(unsigned int a, unsigned int b,
                                            unsigned int c, unsigned int d) {
    union { uint4 u; bf16x8 v; } t;
    t.u = make_uint4(a, b, c, d);
    return t.v;
}
// exp2 all 8 score values of an (A,B) j-tile pair and pack to a K=32 B-fragment
__device__ __forceinline__ bf16x8 exp2pack(f32x4 a, f32x4 b) {
    return u4_to_bf8(
        pk2bf(__builtin_amdgcn_exp2f(a[0]), __builtin_amdgcn_exp2f(a[1])),
        pk2bf(__builtin_amdgcn_exp2f(a[2]), __builtin_amdgcn_exp2f(a[3])),
        pk2bf(__builtin_amdgcn_exp2f(b[0]), __builtin_amdgcn_exp2f(b[1])),
        pk2bf(__builtin_amdgcn_exp2f(b[2]), __builtin_amdgcn_exp2f(b[3])));
}
// LDS chunk swizzle for proj staging: <=2-way banks both directions
__device__ __forceinline__ int xswz(int j, int c8) {
    return c8 ^ (j & 7) ^ ((j >> 3) & 7);
}

// ---------------- prep: Wv -> bf16; [Wq*SCALE2 ; Wk] -> bf16 ----------------
__global__ __launch_bounds__(256) void prep(
    const float* __restrict__ Wq, const float* __restrict__ Wk, const float* __restrict__ Wv,
    unsigned short* __restrict__ Wvbf, unsigned short* __restrict__ Wqkbf)
{
    int g = blockIdx.x * 256 + threadIdx.x;
    const float* src; unsigned short* dst; float sc = 1.0f;
    if (g < 4096)      { src = Wv + g * 4;            dst = Wvbf + g * 4; }
    else if (g < 4608) { int t = g - 4096; src = Wq + t * 4; dst = Wqkbf + t * 4; sc = SCALE2; }
    else               { int t = g - 4608; src = Wk + t * 4; dst = Wqkbf + 2048 + t * 4; }
    float4 v = *(const float4*)src;
    unsigned short h[4] = {f2bf(v.x * sc), f2bf(v.y * sc), f2bf(v.z * sc), f2bf(v.w * sc)};
    *(ushort4*)dst = *(ushort4*)h;
}

// ---------------- proj: q,k,v in one pass (MFMA) ----------------
// qws/kws: [b][plane 0..3][pos][8] bf16. plane2 of k = {1.0,0...}; plane2 of q
// zeroed here, slot0 later filled with -log2(l) by finl. plane3 = 0.
// vws: j-tiled [b][j/16][c][j%16] bf16
__global__ __launch_bounds__(256) void proj(
    const float* __restrict__ x, const unsigned short* __restrict__ Wvbf,
    const unsigned short* __restrict__ Wqkbf,
    const float* __restrict__ bqp, const float* __restrict__ bkp, const float* __restrict__ bvp,
    unsigned short* __restrict__ qws, unsigned short* __restrict__ kws,
    unsigned short* __restrict__ vws)
{
    __shared__ unsigned short xbf[64 * 128];    // [j][c] swizzled chunks
    __shared__ unsigned short outs[128 * 72];   // v-store bounce, pad 72

    int b  = blockIdx.x & 7;
    int j0 = (blockIdx.x >> 3) * 64;
    int tid = threadIdx.x;
    int wid = tid >> 6, lane = tid & 63, n = lane & 15, q4 = lane >> 4;

#pragma unroll
    for (int i = 0; i < 8; i++) {
        int c = (tid >> 4) + 16 * i;
        int jc = (tid & 15) * 4;
        float4 t = *(const float4*)(x + (size_t)(b * C_ + c) * W_ + j0 + jc);
        float tv[4] = {t.x, t.y, t.z, t.w};
#pragma unroll
        for (int cc = 0; cc < 4; cc++) {
            int j = jc + cc;
            xbf[j * 128 + xswz(j, c >> 3) * 8 + (c & 7)] = f2bf(tv[cc]);
        }
    }
    __syncthreads();

    const f32x4 zero = {0.f, 0.f, 0.f, 0.f};
    f32x4 accv[2][4]; f32x4 accq = zero, acck = zero;
#pragma unroll
    for (int os = 0; os < 2; os++)
#pragma unroll
        for (int js = 0; js < 4; js++) accv[os][js] = zero;

#pragma unroll
    for (int kk = 0; kk < 128; kk += 32) {
        bf16x8 av[2], aqf, akf, bx[4];
#pragma unroll
        for (int os = 0; os < 2; os++)
            av[os] = *(const bf16x8*)(Wvbf + (wid * 32 + os * 16 + n) * 128 + kk + q4 * 8);
        aqf = *(const bf16x8*)(Wqkbf + n * 128 + kk + q4 * 8);
        akf = *(const bf16x8*)(Wqkbf + (16 + n) * 128 + kk + q4 * 8);
#pragma unroll
        for (int js = 0; js < 4; js++) {
            int j = js * 16 + n;
            bx[js] = *(const bf16x8*)&xbf[j * 128 + xswz(j, (kk >> 3) + q4) * 8];
        }
#pragma unroll
        for (int os = 0; os < 2; os++)
#pragma unroll
            for (int js = 0; js < 4; js++)
                accv[os][js] = __builtin_amdgcn_mfma_f32_16x16x32_bf16(av[os], bx[js], accv[os][js], 0, 0, 0);
        accq = __builtin_amdgcn_mfma_f32_16x16x32_bf16(aqf, bx[wid], accq, 0, 0, 0);
        acck = __builtin_amdgcn_mfma_f32_16x16x32_bf16(akf, bx[wid], acck, 0, 0, 0);
    }

    // q/k epilogue
    {
        int pos = j0 + wid * 16 + n;
        float q0 = accq[0] + bqp[q4 * 4 + 0] * SCALE2;
        float q1 = accq[1] + bqp[q4 * 4 + 1] * SCALE2;
        float q2 = accq[2] + bqp[q4 * 4 + 2] * SCALE2;
        float q3 = accq[3] + bqp[q4 * 4 + 3] * SCALE2;
        float k0 = acck[0] + bkp[q4 * 4 + 0];
        float k1 = acck[1] + bkp[q4 * 4 + 1];
        float k2 = acck[2] + bkp[q4 * 4 + 2];
        float k3 = acck[3] + bkp[q4 * 4 + 3];
        size_t base = ((size_t)(b * 4 + (q4 >> 1)) * W_ + pos) * 8 + (q4 & 1) * 4;
        *(uint2*)(qws + base) = make_uint2((unsigned)f2bf(q0) | ((unsigned)f2bf(q1) << 16),
                                           (unsigned)f2bf(q2) | ((unsigned)f2bf(q3) << 16));
        *(uint2*)(kws + base) = make_uint2((unsigned)f2bf(k0) | ((unsigned)f2bf(k1) << 16),
                                           (unsigned)f2bf(k2) | ((unsigned)f2bf(k3) << 16));
    }
    // planes 2,3: zero, except k plane2 dim16 = 1.0 (bf16 0x3f80)
    {
        int which = tid >> 7;
        int plane = 2 + ((tid >> 6) & 1);
        int pos = j0 + (tid & 63);
        unsigned short* basep = which ? kws : qws;
        uint4 z = make_uint4(0, 0, 0, 0);
        if (which == 1 && plane == 2) z.x = 0x3f80u;
        *(uint4*)(basep + ((size_t)(b * 4 + plane) * W_ + pos) * 8) = z;
    }

    // v epilogue -> LDS bounce -> j-tiled layout
    float bvv[2][4];
#pragma unroll
    for (int os = 0; os < 2; os++)
#pragma unroll
        for (int r = 0; r < 4; r++) bvv[os][r] = bvp[wid * 32 + os * 16 + q4 * 4 + r];
#pragma unroll
    for (int os = 0; os < 2; os++)
#pragma unroll
        for (int js = 0; js < 4; js++)
#pragma unroll
            for (int r = 0; r < 4; r++) {
                int c = wid * 32 + os * 16 + q4 * 4 + r;
                int j = js * 16 + n;
                outs[c * 72 + j] = f2bf(accv[os][js][r] + bvv[os][r]);
            }
    __syncthreads();
    {
        int p = tid;
#pragma unroll
        for (int rep = 0; rep < 2; rep++, p += 256) {
            int jt_l = p >> 7;          // 0..3
            int c    = p & 127;
            const uint4* src = (const uint4*)&outs[c * 72 + jt_l * 16];
            unsigned short* dst = vws + ((size_t)((b * 256 + (j0 >> 4) + jt_l) * 128 + c)) * 16;
            *(uint4*)(dst + 0) = src[0];
            *(uint4*)(dst + 8) = src[1];
        }
    }
}

// ---------------- row_stats: partial l-sums, w split 4 ways, pipelined ----------------
// rlp[wsp][b][W] = sum over this block's w-quarter of exp2(s2[j,w])
__global__ __launch_bounds__(256) void row_stats(
    const unsigned short* __restrict__ qws, const unsigned short* __restrict__ kws,
    float* __restrict__ rlp)
{
    int blk = blockIdx.x;
    int b = blk & 7;
    int j0 = ((blk >> 3) & 63) * 64;
    int wsp = blk >> 9;                 // 0..3
    int t0 = wsp * 16;                  // 16 key tiles of 64
    int tid = threadIdx.x;
    int wid = tid >> 6, lane = tid & 63, n = lane & 15, q4 = lane >> 4;

    const bf16x8* qbase = (const bf16x8*)qws + (size_t)(b * 4 + q4) * W_;
    const bf16x8* kbase = (const bf16x8*)kws + (size_t)(b * 4 + q4) * W_;
    bf16x8 aq = qbase[j0 + wid * 16 + n];
    const f32x4 zero = {0.f, 0.f, 0.f, 0.f};

    float lt[4] = {0.f, 0.f, 0.f, 0.f};
    bf16x8 k0[4], k1[4];
#pragma unroll
    for (int ws = 0; ws < 4; ws++) {
        k0[ws] = kbase[(t0 + 0) * 64 + ws * 16 + n];
        k1[ws] = kbase[(t0 + 1) * 64 + ws * 16 + n];
    }

#pragma unroll 2
    for (int t = 0; t < 8; t++) {
        f32x4 sa[4], sb[4];
#pragma unroll
        for (int ws = 0; ws < 4; ws++)
            sa[ws] = __builtin_amdgcn_mfma_f32_16x16x32_bf16(aq, k0[ws], zero, 0, 0, 0);
#pragma unroll
        for (int ws = 0; ws < 4; ws++)
            sb[ws] = __builtin_amdgcn_mfma_f32_16x16x32_bf16(aq, k1[ws], zero, 0, 0, 0);
        // prefetch next pair (wrap within strip; harmless reload on last iter)
        int ta = t0 + ((2 * t + 2) & 15), tb = t0 + ((2 * t + 3) & 15);
#pragma unroll
        for (int ws = 0; ws < 4; ws++) {
            k0[ws] = kbase[ta * 64 + ws * 16 + n];
            k1[ws] = kbase[tb * 64 + ws * 16 + n];
        }
#pragma unroll
        for (int ws = 0; ws < 4; ws++)
#pragma unroll
            for (int r = 0; r < 4; r++) {
                lt[r] += __builtin_amdgcn_exp2f(sa[ws][r]);
                lt[r] += __builtin_amdgcn_exp2f(sb[ws][r]);
            }
    }
#pragma unroll
    for (int mask = 1; mask < 16; mask <<= 1)
#pragma unroll
        for (int r = 0; r < 4; r++) lt[r] += __shfl_xor(lt[r], mask, 64);
    if (n == 0) {
        f32x4 l4 = {lt[0], lt[1], lt[2], lt[3]};
        *(f32x4*)(rlp + (size_t)wsp * 32768 + (size_t)b * W_ + j0 + wid * 16 + q4 * 4) = l4;
    }
}

// ---------------- finl: l = sum of 4 partials; q plane2 slot0 <- -log2(l) ----------------
__global__ __launch_bounds__(256) void finl(const float* __restrict__ rlp,
                                            unsigned short* __restrict__ qws)
{
    int g = blockIdx.x * 256 + threadIdx.x;   // 32768 = B*W
    int b = g >> 12, j = g & (W_ - 1);
    float l = rlp[g] + rlp[32768 + g] + rlp[65536 + g] + rlp[98304 + g];
    qws[((size_t)(b * 4 + 2) * W_ + j) * 8] = f2bf(-__builtin_amdgcn_logf(l));
}

// ---------------- attn_out: barrier-free K-loop, 2-stage software pipeline ----------------
// Wave owns j-slices {it*128 + wid*16, +64}; S C-layout == PV B-fragment under the
// k-slot<->j bijection; v A-frags from j-tiled vws. Cross-wave reduce at the end.
__global__ __launch_bounds__(256, 2) void attn_out(
    const float* __restrict__ x, const unsigned short* __restrict__ qws,
    const unsigned short* __restrict__ kws, const unsigned short* __restrict__ vws,
    float* __restrict__ out)
{
    __shared__ float red[2][128 * 68];   // 69.6 KB: reduction + store bounce

    int b  = blockIdx.x & 7;
    int w0 = (blockIdx.x >> 3) * 64;
    int tid = threadIdx.x;
    int wid = tid >> 6, lane = tid & 63, n = lane & 15, q4 = lane >> 4;

    const bf16x8* qbase = (const bf16x8*)qws + (size_t)(b * 4 + q4) * W_;
    const bf16x8* kbase = (const bf16x8*)kws + (size_t)(b * 4 + q4) * W_;
    const unsigned short* vtb = vws + (size_t)b * 256 * 128 * 16;

    bf16x8 bk[4];
#pragma unroll
    for (int ws = 0; ws < 4; ws++) bk[ws] = kbase[w0 + ws * 16 + n];

    const f32x4 zero = {0.f, 0.f, 0.f, 0.f};
    f32x4 acc[8][4];   // [mt(c)][nt(w)]
#pragma unroll
    for (int mt = 0; mt < 8; mt++)
#pragma unroll
        for (int nt = 0; nt < 4; nt++) acc[mt][nt] = zero;

    // ---- pipeline prologue (it = 0) ----
    bf16x8 aqA = qbase[wid * 16 + n];
    bf16x8 aqB = qbase[64 + wid * 16 + n];
    uint2 vfA[8], vfB[8];
#pragma unroll
    for (int mt = 0; mt < 8; mt++) {
        int c = mt * 16 + n;
        vfA[mt] = *(const uint2*)(vtb + (size_t)((wid) * 128 + c) * 16 + q4 * 4);
        vfB[mt] = *(const uint2*)(vtb + (size_t)((wid + 4) * 128 + c) * 16 + q4 * 4);
    }
    f32x4 sA[4], sB[4];
#pragma unroll
    for (int ws = 0; ws < 4; ws++) {
        sA[ws] = __builtin_amdgcn_mfma_f32_16x16x32_bf16(aqA, bk[ws], zero, 0, 0, 0);
        sB[ws] = __builtin_amdgcn_mfma_f32_16x16x32_bf16(aqB, bk[ws], zero, 0, 0, 0);
    }
    aqA = qbase[128 + wid * 16 + n];          // q frags for it=1
    aqB = qbase[128 + 64 + wid * 16 + n];
    bf16x8 bfrag[4];
#pragma unroll
    for (int ws = 0; ws < 4; ws++) bfrag[ws] = exp2pack(sA[ws], sB[ws]);

    for (int it = 0; it < 32; it++) {
        int itn = (it + 1) & 31;
        // (a) v-fragment prefetch for it+1
        uint2 vfA_n[8], vfB_n[8];
        int jtA_n = itn * 8 + wid, jtB_n = jtA_n + 4;
#pragma unroll
        for (int mt = 0; mt < 8; mt++) {
            int c = mt * 16 + n;
            vfA_n[mt] = *(const uint2*)(vtb + (size_t)(jtA_n * 128 + c) * 16 + q4 * 4);
            vfB_n[mt] = *(const uint2*)(vtb + (size_t)(jtB_n * 128 + c) * 16 + q4 * 4);
        }
        // (b) S-MFMAs for it+1 (aq regs hold it+1 frags)
#pragma unroll
        for (int ws = 0; ws < 4; ws++) {
            sA[ws] = __builtin_amdgcn_mfma_f32_16x16x32_bf16(aqA, bk[ws], zero, 0, 0, 0);
            sB[ws] = __builtin_amdgcn_mfma_f32_16x16x32_bf16(aqB, bk[ws], zero, 0, 0, 0);
        }
        // (c) q loads for it+2
        int itn2 = (it + 2) & 31;
        aqA = qbase[itn2 * 128 + wid * 16 + n];
        aqB = qbase[itn2 * 128 + 64 + wid * 16 + n];
        // (d) PV for it (consumes bfrag + vf regs)
#pragma unroll
        for (int mt = 0; mt < 8; mt++) {
            bf16x8 af = u4_to_bf8(vfA[mt].x, vfA[mt].y, vfB[mt].x, vfB[mt].y);
#pragma unroll
            for (int nt = 0; nt < 4; nt++)
                acc[mt][nt] = __builtin_amdgcn_mfma_f32_16x16x32_bf16(af, bfrag[nt], acc[mt][nt], 0, 0, 0);
        }
        // (e) exp2/pack for it+1 -> next bfrag (trans pipe overlaps PV via co-resident waves)
#pragma unroll
        for (int ws = 0; ws < 4; ws++) bfrag[ws] = exp2pack(sA[ws], sB[ws]);
        // rotate v-frag registers
#pragma unroll
        for (int mt = 0; mt < 8; mt++) { vfA[mt] = vfA_n[mt]; vfB[mt] = vfB_n[mt]; }
    }

    // ---- cross-wave reduction ----
    if (wid >= 2) {
        float* buf = red[wid - 2];
#pragma unroll
        for (int mt = 0; mt < 8; mt++)
#pragma unroll
            for (int nt = 0; nt < 4; nt++)
#pragma unroll
                for (int r = 0; r < 4; r++)
                    buf[(mt * 16 + q4 * 4 + r) * 68 + nt * 16 + n] = acc[mt][nt][r];
    }
    __syncthreads();
    if (wid < 2) {
        const float* buf = red[wid];
#pragma unroll
        for (int mt = 0; mt < 8; mt++)
#pragma unroll
            for (int nt = 0; nt < 4; nt++)
#pragma unroll
                for (int r = 0; r < 4; r++)
                    acc[mt][nt][r] += buf[(mt * 16 + q4 * 4 + r) * 68 + nt * 16 + n];
    }
    __syncthreads();
    if (wid == 1) {
        float* buf = red[0];
#pragma unroll
        for (int mt = 0; mt < 8; mt++)
#pragma unroll
            for (int nt = 0; nt < 4; nt++)
#pragma unroll
                for (int r = 0; r < 4; r++)
                    buf[(mt * 16 + q4 * 4 + r) * 68 + nt * 16 + n] = acc[mt][nt][r];
    }
    __syncthreads();
    if (wid == 0) {
        float* buf = red[0];
#pragma unroll
        for (int mt = 0; mt < 8; mt++)
#pragma unroll
            for (int nt = 0; nt < 4; nt++)
#pragma unroll
                for (int r = 0; r < 4; r++) {
                    int idx = (mt * 16 + q4 * 4 + r) * 68 + nt * 16 + n;
                    buf[idx] = acc[mt][nt][r] + buf[idx];
                }
    }
    __syncthreads();
    // coalesced store: out = red[0] + x
    {
#pragma unroll
        for (int u = 0; u < 8; u++) {
            int k = tid + 256 * u;          // 2048 float4 slots
            int c = k >> 4, wseg = (k & 15) * 4;
            size_t gidx = (size_t)(b * C_ + c) * W_ + w0 + wseg;
            float4 xv = *(const float4*)(x + gidx);
            const float* s = &red[0][c * 68 + wseg];
            float4 o = make_float4(s[0] + xv.x, s[1] + xv.y, s[2] + xv.z, s[3] + xv.w);
            *(float4*)(out + gidx) = o;
        }
    }
}

extern "C" void kernel_launch(void* const* d_in, const int* in_sizes, int n_in,
                              void* d_out, int out_size, void* d_ws, size_t ws_size,
                              hipStream_t stream)
{
    const float* x  = (const float*)d_in[0];
    const float* Wq = (const float*)d_in[1];
    const float* bq = (const float*)d_in[2];
    const float* Wk = (const float*)d_in[3];
    const float* bk = (const float*)d_in[4];
    const float* Wv = (const float*)d_in[5];
    const float* bv = (const float*)d_in[6];
    float* out = (float*)d_out;

    unsigned short* qws  = (unsigned short*)d_ws;        // [B][4][W][8] bf16 = 2MB
    unsigned short* kws  = qws + (size_t)1048576;        // [B][4][W][8] bf16 = 2MB
    unsigned short* vws  = kws + (size_t)1048576;        // [B][W/16][C][16] bf16 = 8MB
    unsigned short* Wvbf = vws + (size_t)4194304;        // [128][128]
    unsigned short* Wqkbf = Wvbf + 16384;                // [32][128] (q rows pre-scaled)
    float* rlp = (float*)(Wqkbf + 4096);                 // [4][B][W] partial l-sums

    prep<<<20, 256, 0, stream>>>(Wq, Wk, Wv, Wvbf, Wqkbf);
    proj<<<512, 256, 0, stream>>>(x, Wvbf, Wqkbf, bq, bk, bv, qws, kws, vws);
    row_stats<<<2048, 256, 0, stream>>>(qws, kws, rlp);
    finl<<<128, 256, 0, stream>>>(rlp, qws);
    attn_out<<<512, 256, 0, stream>>>(x, qws, kws, vws, out);
}